// Round 16
// baseline (44.854 us; speedup 1.0000x reference)
//
#include <hip/hip_runtime.h>

typedef _Float16 f16x8 __attribute__((ext_vector_type(8)));
typedef _Float16 f16x4 __attribute__((ext_vector_type(4)));
typedef float    f32x4 __attribute__((ext_vector_type(4)));
typedef unsigned int u32x4 __attribute__((ext_vector_type(4)));

constexpr int NTOK   = 1568;       // T*H*W = 8*14*14
constexpr int NHEADS = 8;
constexpr int NCH    = 512;
constexpr int NC32   = 52;         // 32-token chunks, padded to 1664 tokens (q-side only; k-loop uses 49)
constexpr float SK   = 0.15014030f; // 0.125*sqrt(log2 e): (q*SK)·(k*SK) = s*log2e/64 -> p = exp2(.)
constexpr size_t IMG_BH = (size_t)NC32 * 4096;   // 212992 B per (bh) per image

// ---- pre-pass: build fragment-major K and V images (every frag = contiguous 1KB, lane*16) ----
// K frag (c16 = tok/16, ks): slot(l15,grp,j) = x[tok=c16*16+l15][d=ks*32+8grp+j] * SK
// V frag (c32 = tok/32, db): slot(l15,grp,j) = x[tok=c32*32+16*(j>>2)+4grp+(j&3)][d=db*16+l15]
__global__ __launch_bounds__(256)
void prep_kernel(const float* __restrict__ x, char* __restrict__ Kimg, char* __restrict__ Vimg)
{
    const int bh = blockIdx.x, c32 = blockIdx.y;
    const int b = bh >> 3, h = bh & 7;
    const int t = threadIdx.x;
    const int f = t >> 6, l = t & 63, l15 = l & 15, grp = l >> 4;

    char* Kg = Kimg + (size_t)bh * IMG_BH + (size_t)(c32 * 4 + f) * 1024 + l * 16;
    char* Vg = Vimg + (size_t)bh * IMG_BH + (size_t)(c32 * 4 + f) * 1024 + l * 16;

    const int n0 = c32 * 32;
    if (n0 >= NTOK) {                       // pure padding chunk
        f16x8 z;
#pragma unroll
        for (int j = 0; j < 8; ++j) z[j] = (_Float16)0.f;
        *(f16x8*)Kg = z; *(f16x8*)Vg = z;
        return;
    }

    __shared__ _Float16 kbuf[32][72];       // [tok][d], scaled
    __shared__ _Float16 vbuf[64][40];       // [d][tok]

    const int tok = t & 31, dhi = t >> 5;   // coalesced: 8 x 128B segments per pass
#pragma unroll
    for (int p = 0; p < 8; ++p) {
        const int d = 8 * p + dhi;
        const float v = x[((size_t)b * NCH + d * NHEADS + h) * NTOK + n0 + tok];
        kbuf[tok][d] = (_Float16)(v * SK);
        vbuf[d][tok] = (_Float16)v;
    }
    __syncthreads();

    // K frag f: cb = f>>1 (16-tok half), ks = f&1
    *(f16x8*)Kg = *(const f16x8*)&kbuf[(f >> 1) * 16 + l15][(f & 1) * 32 + grp * 8];
    // V frag db = f: token quads {4grp..+3} and {16+4grp..+3}
    f16x4 va = *(const f16x4*)&vbuf[f * 16 + l15][4 * grp];
    f16x4 vb = *(const f16x4*)&vbuf[f * 16 + l15][16 + 4 * grp];
    f16x8 vv;
#pragma unroll
    for (int j = 0; j < 4; ++j) { vv[j] = va[j]; vv[4 + j] = vb[j]; }
    *(f16x8*)Vg = vv;
}

// pack 8 exp2(s) values into one P fragment — pure register ops, no union/memory
static __device__ __forceinline__ f16x8 make_bp(f32x4 sA, f32x4 sB)
{
    u32x4 w;
    w[0] = __builtin_bit_cast(unsigned int,
        __builtin_amdgcn_cvt_pkrtz(__builtin_amdgcn_exp2f(sA[0]), __builtin_amdgcn_exp2f(sA[1])));
    w[1] = __builtin_bit_cast(unsigned int,
        __builtin_amdgcn_cvt_pkrtz(__builtin_amdgcn_exp2f(sA[2]), __builtin_amdgcn_exp2f(sA[3])));
    w[2] = __builtin_bit_cast(unsigned int,
        __builtin_amdgcn_cvt_pkrtz(__builtin_amdgcn_exp2f(sB[0]), __builtin_amdgcn_exp2f(sB[1])));
    w[3] = __builtin_bit_cast(unsigned int,
        __builtin_amdgcn_cvt_pkrtz(__builtin_amdgcn_exp2f(sB[2]), __builtin_amdgcn_exp2f(sB[3])));
    return __builtin_bit_cast(f16x8, w);
}

// full per-chunk compute: QK S^T (2 q-subgroups) -> exp/pack -> denominator + PV
static __device__ __forceinline__ void chunk_compute(
    const f16x8& k0, const f16x8& k1, const f16x8& k2, const f16x8& k3,
    const f16x8& v0, const f16x8& v1, const f16x8& v2, const f16x8& v3,
    const f16x8 (&aq)[2][2], const f16x8& ones,
    f32x4 (&oacc)[2][4], f32x4 (&lacc)[2])
{
    const f32x4 z4 = {0.f, 0.f, 0.f, 0.f};
#pragma unroll
    for (int sub = 0; sub < 2; ++sub) {
        f32x4 sA = __builtin_amdgcn_mfma_f32_16x16x32_f16(k0, aq[sub][0], z4, 0, 0, 0);
        sA = __builtin_amdgcn_mfma_f32_16x16x32_f16(k1, aq[sub][1], sA, 0, 0, 0);
        f32x4 sB = __builtin_amdgcn_mfma_f32_16x16x32_f16(k2, aq[sub][0], z4, 0, 0, 0);
        sB = __builtin_amdgcn_mfma_f32_16x16x32_f16(k3, aq[sub][1], sB, 0, 0, 0);
        const f16x8 bp = make_bp(sA, sB);   // slot j = token 16*(j>>2)+4grp+(j&3)
        lacc[sub]    = __builtin_amdgcn_mfma_f32_16x16x32_f16(ones, bp, lacc[sub], 0, 0, 0);
        oacc[sub][0] = __builtin_amdgcn_mfma_f32_16x16x32_f16(v0, bp, oacc[sub][0], 0, 0, 0);
        oacc[sub][1] = __builtin_amdgcn_mfma_f32_16x16x32_f16(v1, bp, oacc[sub][1], 0, 0, 0);
        oacc[sub][2] = __builtin_amdgcn_mfma_f32_16x16x32_f16(v2, bp, oacc[sub][2], 0, 0, 0);
        oacc[sub][3] = __builtin_amdgcn_mfma_f32_16x16x32_f16(v3, bp, oacc[sub][3], 0, 0, 0);
    }
}

// ---- main attention: LDS-shared chunk pipeline, QBLK=128 (4 waves x 2 subs), no combine ----
// Per chunk: issue next-chunk loads (2/thread) -> compute current from LDS (8x ds_read_b128,
// stride-16 conflict-free) -> ds_write staged regs -> ONE barrier. 2-buffer hazard: the write
// target holds chunk c-1, which every wave finished reading before the previous barrier.
__global__ __launch_bounds__(256, 3)
void attn_fwd(const char* __restrict__ Kimg, const char* __restrict__ Vimg,
              float* __restrict__ out)
{
    // XCD-aware bijective remap (416 = 8*52): 4 bh per XCD -> both images L2-resident
    const int orig = blockIdx.x;
    const int wgid = (orig & 7) * 52 + (orig >> 3);
    const int qt = wgid % 13, bh = wgid / 13;       // qt: 128-row q-tile (13*128 = 1664 padded)
    const int b = bh >> 3, head = bh & 7;
    const int t = threadIdx.x, wave = t >> 6, lane = t & 63;
    const int l15 = lane & 15, grp = lane >> 4;

    __shared__ __align__(16) char kls[2][4096];     // staged K chunk (4 frags x 1KB)
    __shared__ __align__(16) char vls[2][4096];     // staged V chunk

    const char* Kb = Kimg + (size_t)bh * IMG_BH;
    const char* Vb = Vimg + (size_t)bh * IMG_BH;

    // Q fragments: 16-row subtile s16 = qt*8 + wave*2 + sub (padded image -> always in-bounds)
    f16x8 aq[2][2];
#pragma unroll
    for (int sub = 0; sub < 2; ++sub)
#pragma unroll
        for (int ks = 0; ks < 2; ++ks)
            aq[sub][ks] = *(const f16x8*)(Kb + (size_t)((qt * 8 + wave * 2 + sub) * 2 + ks) * 1024 + lane * 16);

    f16x8 ones;
#pragma unroll
    for (int j = 0; j < 8; ++j) ones[j] = (_Float16)1.f;

    f32x4 oacc[2][4];
    f32x4 lacc[2];
#pragma unroll
    for (int s = 0; s < 2; ++s) {
        lacc[s] = f32x4{0.f, 0.f, 0.f, 0.f};
#pragma unroll
        for (int db = 0; db < 4; ++db) oacc[s][db] = f32x4{0.f, 0.f, 0.f, 0.f};
    }

    const int soff = t * 16;            // linear staging: thread t owns bytes [16t,16t+16)

    // prologue: stage chunk 0
    {
        f16x8 sk = *(const f16x8*)(Kb + soff);
        f16x8 sv = *(const f16x8*)(Vb + soff);
        *(f16x8*)&kls[0][soff] = sk;
        *(f16x8*)&vls[0][soff] = sv;
    }
    __syncthreads();

    for (int c = 0; c < 49; ++c) {      // 49 x 32 = 1568 tokens exactly (no k padding)
        const int cur = c & 1, nxt = cur ^ 1;

        // issue next chunk's staging loads early (c+1 <= 49 < 52: inside padded image)
        f16x8 sk = *(const f16x8*)(Kb + (size_t)(c + 1) * 4096 + soff);
        f16x8 sv = *(const f16x8*)(Vb + (size_t)(c + 1) * 4096 + soff);

        // compute chunk c from LDS (frag reads: 64 lanes x consecutive 16B -> conflict-free)
        f16x8 k0 = *(const f16x8*)&kls[cur][lane * 16];
        f16x8 k1 = *(const f16x8*)&kls[cur][1024 + lane * 16];
        f16x8 k2 = *(const f16x8*)&kls[cur][2048 + lane * 16];
        f16x8 k3 = *(const f16x8*)&kls[cur][3072 + lane * 16];
        f16x8 v0 = *(const f16x8*)&vls[cur][lane * 16];
        f16x8 v1 = *(const f16x8*)&vls[cur][1024 + lane * 16];
        f16x8 v2 = *(const f16x8*)&vls[cur][2048 + lane * 16];
        f16x8 v3 = *(const f16x8*)&vls[cur][3072 + lane * 16];
        chunk_compute(k0, k1, k2, k3, v0, v1, v2, v3, aq, ones, oacc, lacc);

        // write staged regs into the other buffer (its old content = chunk c-1, fully consumed)
        *(f16x8*)&kls[nxt][soff] = sk;
        *(f16x8*)&vls[nxt][soff] = sv;
        __syncthreads();
    }

    // ---- store: each wave owns its 32 q-rows outright (full k-range -> no combine) ----
#pragma unroll
    for (int sub = 0; sub < 2; ++sub) {
        const int s16 = qt * 8 + wave * 2 + sub;
        if (s16 < 98) {                 // 98*16 = 1568: wave-uniform validity
            const int qrow = s16 * 16 + l15;
            const float inv = 1.0f / lacc[sub][0];   // denominator for column q = l15
#pragma unroll
            for (int db = 0; db < 4; ++db)
#pragma unroll
                for (int q = 0; q < 4; ++q) {
                    const int d = db * 16 + 4 * grp + q;    // O^T: row=d, col=q
                    out[((size_t)b * NCH + (size_t)d * NHEADS + head) * NTOK + qrow] = oacc[sub][db][q] * inv;
                }
        }
    }
}

extern "C" void kernel_launch(void* const* d_in, const int* in_sizes, int n_in,
                              void* d_out, int out_size, void* d_ws, size_t ws_size,
                              hipStream_t stream)
{
    const float* x = (const float*)d_in[0];
    float* out     = (float*)d_out;

    char* Kimg = (char*)d_ws;                       // 32 * 208KB = 6.8 MB
    char* Vimg = (char*)d_ws + 32 * IMG_BH;         // + 6.8 MB

    dim3 pgrid(32, NC32);                           // 32 bh x 52 chunks
    prep_kernel<<<pgrid, 256, 0, stream>>>(x, Kimg, Vimg);

    attn_fwd<<<416, 256, 0, stream>>>(Kimg, Vimg, out);   // 13 q-tiles x 32 bh, XCD-remapped
}